// Round 1
// baseline (455.247 us; speedup 1.0000x reference)
//
#include <hip/hip_runtime.h>
#include <hip/hip_bf16.h>

#define DEVINL __device__ __forceinline__

DEVINL float readlane_f(float v, int lane) {
  return __uint_as_float(__builtin_amdgcn_readlane(__float_as_uint(v), lane));
}

// select r[k] for k in [M0, M0+8), constant-indexed tree (works for uniform or per-lane k)
template<int M0>
DEVINL float reg_select8(const float (&r)[32], int k) {
  float a0 = (k & 4) ? r[M0 + 4] : r[M0 + 0];
  float a1 = (k & 4) ? r[M0 + 5] : r[M0 + 1];
  float a2 = (k & 4) ? r[M0 + 6] : r[M0 + 2];
  float a3 = (k & 4) ? r[M0 + 7] : r[M0 + 3];
  float b0 = (k & 2) ? a2 : a0;
  float b1 = (k & 2) ? a3 : a1;
  return (k & 1) ? b1 : b0;
}

// One Householder similarity step at pivot column k (M0 <= k < M0+8).
// Row j of C lives in lane j's registers r[0..31]. Lanes 32..63 mirror lanes 0..31
// (their v is masked to 0 so they contribute nothing to reductions).
template<int M0>
DEVINL void house_step(float (&r)[32], int k, int lane, volatile float* ew) {
  float xj = reg_select8<M0>(r, k);           // x_j = C[j][k]
  const bool act = (lane > k) && (lane < 32); // support of the Householder vector
  float xm = act ? xj : 0.0f;

  float nn = xm * xm;                          // ||x||^2
  #pragma unroll
  for (int off = 1; off < 64; off <<= 1) nn += __shfl_xor(nn, off, 64);

  float x0 = readlane_f(xm, k + 1);
  float xnorm = sqrtf(nn);
  float alpha = -copysignf(xnorm, x0);         // new subdiagonal e_k
  float denom = nn - alpha * x0;               // = ||x||^2 + |x0|*||x|| >= 0
  float beta = (denom > 1e-20f) ? (1.0f / denom) : 0.0f;  // beta = 2/v'v

  float vj = act ? (xm - ((lane == k + 1) ? alpha : 0.0f)) : 0.0f;

  float sv[32];
  #pragma unroll
  for (int m = M0; m < 32; ++m) sv[m] = readlane_f(vj, m);   // uniform -> SGPR

  float p = 0.0f;                              // p_j = (C v)_j
  #pragma unroll
  for (int m = M0; m < 32; ++m) p = fmaf(r[m], sv[m], p);
  float pb = beta * p;

  float g = pb * vj;                           // g = v' (beta C v)
  #pragma unroll
  for (int off = 1; off < 64; off <<= 1) g += __shfl_xor(g, off, 64);

  float wj = fmaf(-(0.5f * beta * g), vj, pb); // w = beta*C*v - (beta*g/2) v

  float sw[32];
  #pragma unroll
  for (int m = M0; m < 32; ++m) sw[m] = readlane_f(wj, m);

  // C <- C - v w' - w v'  (full-width over m>=M0; self-consistently finalizes
  // row/col k since w_k = 1 and v_k = 0)
  #pragma unroll
  for (int m = M0; m < 32; ++m) r[m] -= vj * sw[m] + wj * sv[m];

  if (lane == 0) ew[k] = alpha;
}

__global__ __launch_bounds__(256) void Correlation_85134841741354_kernel(
    const float* __restrict__ A, float* __restrict__ out, int M) {
  const int lane = threadIdx.x & 63;
  const int wave = threadIdx.x >> 6;
  const int mol  = blockIdx.x * 4 + wave;
  if (mol >= M) return;
  const int j    = lane & 31;   // row of C owned by this lane
  const int half = lane >> 5;   // feature half (Gram phase)

  __shared__ float lds_e[4][32];
  volatile float* ew = &lds_e[wave][0];

  const float* Am   = A + (size_t)mol * (32 * 128);
  const float* ownp = Am + j * 128 + half * 64;
  const float* bb   = Am + half * 64;

  // ---------------- Gram: r[m] = sum_f A[j][f] * A[m][f] ----------------
  float r[32];
  #pragma unroll
  for (int m = 0; m < 32; ++m) r[m] = 0.0f;

  #pragma unroll 1
  for (int fb = 0; fb < 4; ++fb) {            // 16 floats (= one 64B line) per block
    float4 o0 = *(const float4*)(ownp + fb * 16 + 0);
    float4 o1 = *(const float4*)(ownp + fb * 16 + 4);
    float4 o2 = *(const float4*)(ownp + fb * 16 + 8);
    float4 o3 = *(const float4*)(ownp + fb * 16 + 12);
    #pragma unroll
    for (int m = 0; m < 32; ++m) {
      const float* bm = bb + m * 128 + fb * 16;   // uniform per half-wave
      float4 b0 = *(const float4*)(bm + 0);
      float4 b1 = *(const float4*)(bm + 4);
      float4 b2 = *(const float4*)(bm + 8);
      float4 b3 = *(const float4*)(bm + 12);
      float s = r[m];
      s = fmaf(o0.x, b0.x, s); s = fmaf(o0.y, b0.y, s);
      s = fmaf(o0.z, b0.z, s); s = fmaf(o0.w, b0.w, s);
      s = fmaf(o1.x, b1.x, s); s = fmaf(o1.y, b1.y, s);
      s = fmaf(o1.z, b1.z, s); s = fmaf(o1.w, b1.w, s);
      s = fmaf(o2.x, b2.x, s); s = fmaf(o2.y, b2.y, s);
      s = fmaf(o2.z, b2.z, s); s = fmaf(o2.w, b2.w, s);
      s = fmaf(o3.x, b3.x, s); s = fmaf(o3.y, b3.y, s);
      s = fmaf(o3.z, b3.z, s); s = fmaf(o3.w, b3.w, s);
      r[m] = s;
    }
  }
  // combine feature halves: lanes j and j+32 hold partial sums of the same row
  #pragma unroll
  for (int m = 0; m < 32; ++m) r[m] += __shfl_xor(r[m], 32, 64);

  // ---------------- Householder tridiagonalization ----------------
  #pragma unroll 1
  for (int k = 0; k < 8; ++k)   house_step<0 >(r, k, lane, ew);
  #pragma unroll 1
  for (int k = 8; k < 16; ++k)  house_step<8 >(r, k, lane, ew);
  #pragma unroll 1
  for (int k = 16; k < 24; ++k) house_step<16>(r, k, lane, ew);
  #pragma unroll 1
  for (int k = 24; k < 31; ++k) house_step<24>(r, k, lane, ew);

  // gather tridiagonal (wave-uniform scalars)
  float sd[32];
  #pragma unroll
  for (int i = 0; i < 32; ++i) sd[i] = readlane_f(r[i], i);
  float se2[31];
  #pragma unroll
  for (int i = 0; i < 31; ++i) { float e = ew[i]; se2[i] = e * e; }

  // ---------------- Gershgorin bracket (lanes 0..31 valid) ----------------
  float s0 = reg_select8<0 >(r, j & 7);
  float s1 = reg_select8<8 >(r, j & 7);
  float s2 = reg_select8<16>(r, j & 7);
  float s3 = reg_select8<24>(r, j & 7);
  float t0 = (j & 8) ? s1 : s0;
  float t1 = (j & 8) ? s3 : s2;
  float dj = (j & 16) ? t1 : t0;               // d_j per lane

  float e_a = ew[(j < 31) ? j : 30];
  float ehi = (j < 31) ? e_a : 0.0f;
  float e_b = ew[(j >= 1) ? (j - 1) : 0];
  float elo = (j >= 1) ? e_b : 0.0f;
  float rad = fabsf(ehi) + fabsf(elo);
  float glo = (lane < 32) ? (dj - rad) : 3.4e38f;
  float ghi = (lane < 32) ? (dj + rad) : -3.4e38f;
  #pragma unroll
  for (int off = 1; off < 64; off <<= 1) {
    glo = fminf(glo, __shfl_xor(glo, off, 64));
    ghi = fmaxf(ghi, __shfl_xor(ghi, off, 64));
  }
  float lo = fmaxf(glo - 1e-3f, 0.0f);         // C = A A' is PSD
  float hi = ghi + 1e-3f;

  // ---------------- Sturm bisection, 64 sigma points / round ----------------
  #pragma unroll 1
  for (int rr = 0; rr < 3; ++rr) {
    float stp = (hi - lo) * (1.0f / 65.0f);
    float sig = fmaf(stp, (float)(lane + 1), lo);
    float q = sd[0] - sig;
    int cnt = (q < 0.0f) ? 1 : 0;
    #pragma unroll
    for (int i = 1; i < 32; ++i) {
      float qs = (fabsf(q) < 1e-12f) ? ((q < 0.0f) ? -1e-12f : 1e-12f) : q;
      q = (sd[i] - sig) - se2[i - 1] / qs;
      cnt += (q < 0.0f) ? 1 : 0;
    }
    unsigned long long mask = __ballot(cnt >= 1);   // lane's sigma exceeds lambda_min?
    int b = (mask == 0ull) ? 64 : (__ffsll(mask) - 1);
    float nlo = fmaf(stp, (float)b, lo);
    float nhi = (b == 64) ? hi : fmaf(stp, (float)(b + 1), lo);
    lo = nlo; hi = nhi;
  }

  if (lane == 0) out[mol] = 0.5f * (lo + hi);
}

extern "C" void kernel_launch(void* const* d_in, const int* in_sizes, int n_in,
                              void* d_out, int out_size, void* d_ws, size_t ws_size,
                              hipStream_t stream) {
  const float* A = (const float*)d_in[0];
  float* out = (float*)d_out;
  int n_atoms = in_sizes[1];          // 262144
  int M = n_atoms / 32;               // 8192 molecules
  int blocks = (M + 3) / 4;           // 4 molecules (waves) per 256-thread block
  hipLaunchKernelGGL(Correlation_85134841741354_kernel,
                     dim3(blocks), dim3(256), 0, stream, A, out, M);
}

// Round 2
// 336.526 us; speedup vs baseline: 1.3528x; 1.3528x over previous
//
#include <hip/hip_runtime.h>
#include <hip/hip_bf16.h>

#define DEVINL __device__ __forceinline__

DEVINL float readlane_f(float v, int lane) {
  return __uint_as_float(__builtin_amdgcn_readlane(__float_as_uint(v), lane));
}
DEVINL float rcp_f(float x) { return __builtin_amdgcn_rcpf(x); }

DEVINL float wave_sum(float x) {
  #pragma unroll
  for (int off = 1; off < 64; off <<= 1) x += __shfl_xor(x, off, 64);
  return x;
}

// One Householder similarity step at compile-time pivot K.
// Row j of C lives in lane j's registers r[0..31]; lanes 32..63 mirror j-32.
// Only the trailing block (rows/cols K+1..31) is updated; d_K/e_K recorded to LDS.
template<int K>
DEVINL void house_step(float (&r)[32], int lane, volatile float* d_, volatile float* e_) {
  float dK = readlane_f(r[K], K);              // diagonal entry, frozen from here on
  const bool act = (lane > K) && (lane < 32);  // support of the Householder vector
  float xm = act ? r[K] : 0.0f;                // x = C[K+1..31, K]

  float nn = wave_sum(xm * xm);                // ||x||^2 (uniform)
  float x0 = readlane_f(xm, K + 1);
  float alpha = -copysignf(sqrtf(nn), x0);     // new subdiagonal e_K
  float denom = nn - alpha * x0;               // = ||x||^2 + |x0|*||x|| >= 0
  float beta = (denom > 1e-20f) ? rcp_f(denom) : 0.0f;   // 2 / v'v

  float vj = act ? (xm - ((lane == K + 1) ? alpha : 0.0f)) : 0.0f;

  float sv[32];
  #pragma unroll
  for (int m = K + 1; m < 32; ++m) sv[m] = readlane_f(vj, m);  // uniform -> SGPR

  float p = 0.0f;                              // p_j = (C v)_j over active cols
  #pragma unroll
  for (int m = K + 1; m < 32; ++m) p = fmaf(r[m], sv[m], p);
  float pb = beta * p;

  float g = wave_sum(pb * vj);                 // v' (beta C v); inactive vj=0
  float wj = fmaf(-(0.5f * beta * g), vj, pb); // w = beta C v - (beta g / 2) v
  float wja = act ? wj : 0.0f;                 // mask so finalized rows stay frozen

  float sw[32];
  #pragma unroll
  for (int m = K + 1; m < 32; ++m) sw[m] = readlane_f(wja, m);

  #pragma unroll
  for (int m = K + 1; m < 32; ++m) r[m] -= vj * sw[m] + wja * sv[m];

  if (lane == 0) { d_[K] = dK; e_[K] = alpha; }
}

template<int K>
DEVINL void house_all(float (&r)[32], int lane, volatile float* d_, volatile float* e_) {
  house_step<K>(r, lane, d_, e_);
  if constexpr (K < 30) house_all<K + 1>(r, lane, d_, e_);
}

__global__ __launch_bounds__(256) void Correlation_85134841741354_kernel(
    const float* __restrict__ A, float* __restrict__ out, int M) {
  const int lane = threadIdx.x & 63;
  const int wave = threadIdx.x >> 6;
  const int mol  = blockIdx.x * 4 + wave;
  if (mol >= M) return;
  const int j    = lane & 31;   // row of C owned by this lane
  const int half = lane >> 5;   // feature half (Gram phase)

  __shared__ float lds_d[4][32];
  __shared__ float lds_e[4][32];
  volatile float* d_ = &lds_d[wave][0];
  volatile float* e_ = &lds_e[wave][0];

  const float* Am   = A + (size_t)mol * (32 * 128);
  const float* ownp = Am + j * 128 + half * 64;
  const float* bb   = Am + half * 64;

  // ---------------- Gram: r[m] = sum_f A[j][f] * A[m][f] ----------------
  float r[32];
  #pragma unroll
  for (int m = 0; m < 32; ++m) r[m] = 0.0f;

  #pragma unroll 1
  for (int fb = 0; fb < 4; ++fb) {            // 16 floats per block
    float4 o0 = *(const float4*)(ownp + fb * 16 + 0);
    float4 o1 = *(const float4*)(ownp + fb * 16 + 4);
    float4 o2 = *(const float4*)(ownp + fb * 16 + 8);
    float4 o3 = *(const float4*)(ownp + fb * 16 + 12);
    #pragma unroll
    for (int m = 0; m < 32; ++m) {
      const float* bm = bb + m * 128 + fb * 16;   // uniform per half-wave
      float4 b0 = *(const float4*)(bm + 0);
      float4 b1 = *(const float4*)(bm + 4);
      float4 b2 = *(const float4*)(bm + 8);
      float4 b3 = *(const float4*)(bm + 12);
      float s = r[m];
      s = fmaf(o0.x, b0.x, s); s = fmaf(o0.y, b0.y, s);
      s = fmaf(o0.z, b0.z, s); s = fmaf(o0.w, b0.w, s);
      s = fmaf(o1.x, b1.x, s); s = fmaf(o1.y, b1.y, s);
      s = fmaf(o1.z, b1.z, s); s = fmaf(o1.w, b1.w, s);
      s = fmaf(o2.x, b2.x, s); s = fmaf(o2.y, b2.y, s);
      s = fmaf(o2.z, b2.z, s); s = fmaf(o2.w, b2.w, s);
      s = fmaf(o3.x, b3.x, s); s = fmaf(o3.y, b3.y, s);
      s = fmaf(o3.z, b3.z, s); s = fmaf(o3.w, b3.w, s);
      r[m] = s;
    }
  }
  // combine feature halves: lanes j and j+32 hold partials of the same row
  #pragma unroll
  for (int m = 0; m < 32; ++m) r[m] += __shfl_xor(r[m], 32, 64);

  // ---------------- Householder tridiagonalization (fully unrolled) ----------------
  house_all<0>(r, lane, d_, e_);
  if (lane == 0) { d_[31] = readlane_f(r[31], 31); e_[31] = 0.0f; }

  // ---------------- Gershgorin bracket (per-lane over tridiagonal) ----------------
  float dj  = d_[j];
  float ehi = (j < 31) ? e_[j] : 0.0f;
  float elo = (j >= 1) ? e_[j - 1] : 0.0f;
  float rad = fabsf(ehi) + fabsf(elo);
  float glo = dj - rad;
  float ghi = dj + rad;
  #pragma unroll
  for (int off = 1; off < 64; off <<= 1) {
    glo = fminf(glo, __shfl_xor(glo, off, 64));
    ghi = fmaxf(ghi, __shfl_xor(ghi, off, 64));
  }
  float lo = fmaxf(glo - 1e-3f, 0.0f);         // C = A A' is PSD
  float hi = ghi + 1e-3f;

  // load tridiagonal into (uniform) per-lane registers
  float vd[32];
  #pragma unroll
  for (int i = 0; i < 32; ++i) vd[i] = d_[i];
  float ve2[31];
  #pragma unroll
  for (int i = 0; i < 31; ++i) { float e = e_[i]; ve2[i] = e * e; }

  // ---------------- Sturm bisection, 64 sigma points / round ----------------
  #pragma unroll
  for (int rr = 0; rr < 3; ++rr) {
    float stp = (hi - lo) * (1.0f / 65.0f);
    float sig = fmaf(stp, (float)(lane + 1), lo);
    float q = vd[0] - sig;
    int cnt = (q < 0.0f) ? 1 : 0;
    #pragma unroll
    for (int i = 1; i < 32; ++i) {
      float qs = (fabsf(q) < 1e-12f) ? ((q < 0.0f) ? -1e-12f : 1e-12f) : q;
      q = (vd[i] - sig) - ve2[i - 1] * rcp_f(qs);
      cnt += (q < 0.0f) ? 1 : 0;
    }
    unsigned long long mask = __ballot(cnt >= 1);   // sigma above lambda_min?
    int b = (mask == 0ull) ? 64 : (__ffsll(mask) - 1);
    float nlo = fmaf(stp, (float)b, lo);
    float nhi = (b == 64) ? hi : fmaf(stp, (float)(b + 1), lo);
    lo = nlo; hi = nhi;
  }

  if (lane == 0) out[mol] = 0.5f * (lo + hi);
}

extern "C" void kernel_launch(void* const* d_in, const int* in_sizes, int n_in,
                              void* d_out, int out_size, void* d_ws, size_t ws_size,
                              hipStream_t stream) {
  const float* A = (const float*)d_in[0];
  float* out = (float*)d_out;
  int n_atoms = in_sizes[1];          // 262144
  int M = n_atoms / 32;               // 8192 molecules
  int blocks = (M + 3) / 4;           // 4 molecules (waves) per 256-thread block
  hipLaunchKernelGGL(Correlation_85134841741354_kernel,
                     dim3(blocks), dim3(256), 0, stream, A, out, M);
}

// Round 4
// 311.586 us; speedup vs baseline: 1.4611x; 1.0800x over previous
//
#include <hip/hip_runtime.h>
#include <hip/hip_bf16.h>

#define DEVINL __device__ __forceinline__

DEVINL float rcp_f(float x) { return __builtin_amdgcn_rcpf(x); }

// compiler-level memory barrier: forces LDS stores to be emitted and kills
// stale-value forwarding across it. No instruction generated; within-wave
// DS ordering is guaranteed by hardware (DS pipe is in-order per wave).
#define LDS_FENCE() __asm__ volatile("" ::: "memory")

// reduce within each 32-lane half (xor masks 1..16 never cross the boundary)
DEVINL float half_sum(float x) {
  #pragma unroll
  for (int off = 1; off < 32; off <<= 1) x += __shfl_xor(x, off, 64);
  return x;
}
DEVINL float half_min(float x) {
  #pragma unroll
  for (int off = 1; off < 32; off <<= 1) x = fminf(x, __shfl_xor(x, off, 64));
  return x;
}
DEVINL float half_max(float x) {
  #pragma unroll
  for (int off = 1; off < 32; off <<= 1) x = fmaxf(x, __shfl_xor(x, off, 64));
  return x;
}

// Per-wave LDS scratch; [2] = per half (one molecule per half). 36-float rows
// keep 16B alignment for float4 chunk reads.
struct WaveLds {
  float v[2][36];
  float w[2][36];
  float d[2][36];
  float e[2][36];
};

// One Householder similarity step at compile-time pivot K.
// Lane (half*32 + j) owns row j of its half's 32x32 Gram matrix in r[0..31].
// Broadcast of v/w via per-half LDS staging (single store, fenced, float4 reads).
template<int K>
DEVINL void house_step(float (&r)[32], int j, int lane, float* vbuf, float* wbuf,
                       float* dbuf, float* ebuf) {
  const bool act = (j > K);
  float xm = act ? r[K] : 0.0f;                 // x = C[K+1..31, K] (else 0)

  float nn = half_sum(xm * xm);                 // ||x||^2, uniform per half
  float x0 = __shfl(xm, (lane & 32) + (K + 1), 64);  // x_{K+1}, per-half bcast
  float alpha = -copysignf(sqrtf(nn), x0);      // new subdiagonal e_K
  float denom = nn - alpha * x0;                // = ||x||^2 + |x0| ||x|| >= 0
  float beta = (denom > 1e-20f) ? rcp_f(denom) : 0.0f;  // 2 / v'v

  float vj = act ? (xm - ((j == K + 1) ? alpha : 0.0f)) : 0.0f;
  vbuf[j] = vj;                                 // stage FINAL v, exactly once
  LDS_FENCE();

  constexpr int C0 = (K + 1) / 4;               // first float4 chunk touching v
  float4 vc[8];
  #pragma unroll
  for (int c = C0; c < 8; ++c) vc[c] = *(const float4*)(vbuf + 4 * c);

  float p = 0.0f;                               // p_j = (C v)_j ; v=0 below K+1
  #pragma unroll
  for (int c = C0; c < 8; ++c) {
    p = fmaf(r[4 * c + 0], vc[c].x, p);
    p = fmaf(r[4 * c + 1], vc[c].y, p);
    p = fmaf(r[4 * c + 2], vc[c].z, p);
    p = fmaf(r[4 * c + 3], vc[c].w, p);
  }
  float pb = beta * p;

  float g = half_sum(pb * vj);                  // v' (beta C v)
  float wj = fmaf(-(0.5f * beta * g), vj, pb);  // w = beta C v - (beta g/2) v
  float wja = act ? wj : 0.0f;                  // keep finalized rows frozen
  wbuf[j] = wja;
  LDS_FENCE();

  #pragma unroll
  for (int c = C0; c < 8; ++c) {
    float4 wc = *(const float4*)(wbuf + 4 * c);
    r[4 * c + 0] -= vj * wc.x + wja * vc[c].x;
    r[4 * c + 1] -= vj * wc.y + wja * vc[c].y;
    r[4 * c + 2] -= vj * wc.z + wja * vc[c].z;
    r[4 * c + 3] -= vj * wc.w + wja * vc[c].w;
  }

  if (j == K) { dbuf[K] = r[K]; ebuf[K] = alpha; }  // row K frozen from here on
}

template<int K>
DEVINL void house_all(float (&r)[32], int j, int lane, float* vbuf, float* wbuf,
                      float* dbuf, float* ebuf) {
  house_step<K>(r, j, lane, vbuf, wbuf, dbuf, ebuf);
  if constexpr (K < 30) house_all<K + 1>(r, j, lane, vbuf, wbuf, dbuf, ebuf);
}

__global__ __launch_bounds__(256) void Correlation_85134841741354_kernel(
    const float* __restrict__ A, float* __restrict__ out, int M) {
  const int lane = threadIdx.x & 63;
  const int wave = threadIdx.x >> 6;
  const int j    = lane & 31;            // row owned by this lane
  const int half = lane >> 5;            // which molecule of the pair
  const int mol  = blockIdx.x * 8 + wave * 2 + half;
  if (blockIdx.x * 8 + wave * 2 >= M) return;

  __shared__ WaveLds lds[4];
  float* vbuf = &lds[wave].v[half][0];
  float* wbuf = &lds[wave].w[half][0];
  float* dbuf = &lds[wave].d[half][0];
  float* ebuf = &lds[wave].e[half][0];

  const float* Am   = A + (size_t)mol * (32 * 128);
  const float* ownp = Am + j * 128;

  // ---------------- Gram: r[m] = sum_f A[j][f] * A[m][f] (full 128 feats) ----
  float r[32];
  #pragma unroll
  for (int m = 0; m < 32; ++m) r[m] = 0.0f;

  #pragma unroll 1
  for (int fb = 0; fb < 8; ++fb) {              // 16 features per block
    float4 o0 = *(const float4*)(ownp + fb * 16 + 0);
    float4 o1 = *(const float4*)(ownp + fb * 16 + 4);
    float4 o2 = *(const float4*)(ownp + fb * 16 + 8);
    float4 o3 = *(const float4*)(ownp + fb * 16 + 12);
    #pragma unroll
    for (int m = 0; m < 32; ++m) {
      const float* bm = Am + m * 128 + fb * 16; // uniform per half
      float4 b0 = *(const float4*)(bm + 0);
      float4 b1 = *(const float4*)(bm + 4);
      float4 b2 = *(const float4*)(bm + 8);
      float4 b3 = *(const float4*)(bm + 12);
      float s = r[m];
      s = fmaf(o0.x, b0.x, s); s = fmaf(o0.y, b0.y, s);
      s = fmaf(o0.z, b0.z, s); s = fmaf(o0.w, b0.w, s);
      s = fmaf(o1.x, b1.x, s); s = fmaf(o1.y, b1.y, s);
      s = fmaf(o1.z, b1.z, s); s = fmaf(o1.w, b1.w, s);
      s = fmaf(o2.x, b2.x, s); s = fmaf(o2.y, b2.y, s);
      s = fmaf(o2.z, b2.z, s); s = fmaf(o2.w, b2.w, s);
      s = fmaf(o3.x, b3.x, s); s = fmaf(o3.y, b3.y, s);
      s = fmaf(o3.z, b3.z, s); s = fmaf(o3.w, b3.w, s);
      r[m] = s;
    }
  }

  // ---------------- Householder tridiagonalization (fully unrolled) ----------
  house_all<0>(r, j, lane, vbuf, wbuf, dbuf, ebuf);
  if (j == 31) { dbuf[31] = r[31]; ebuf[31] = 0.0f; }
  LDS_FENCE();

  // ---------------- Gershgorin bracket over the tridiagonal ------------------
  float dj = dbuf[j];
  float eh = ebuf[j];                            // ebuf[31] = 0
  float el = ebuf[(j >= 1) ? (j - 1) : 0];
  if (j == 0) el = 0.0f;
  float rad = fabsf(eh) + fabsf(el);
  float glo = half_min(dj - rad);
  float ghi = half_max(dj + rad);
  float lo = fmaxf(glo - 1e-3f, 0.0f);           // C = A A' is PSD
  float hi = ghi + 1e-3f;

  // load tridiagonal into registers (uniform per half)
  float vd[32], ve2[32];
  #pragma unroll
  for (int c = 0; c < 8; ++c) {
    float4 dc = *(const float4*)(dbuf + 4 * c);
    float4 ec = *(const float4*)(ebuf + 4 * c);
    vd[4 * c + 0] = dc.x; vd[4 * c + 1] = dc.y;
    vd[4 * c + 2] = dc.z; vd[4 * c + 3] = dc.w;
    ve2[4 * c + 0] = ec.x * ec.x; ve2[4 * c + 1] = ec.y * ec.y;
    ve2[4 * c + 2] = ec.z * ec.z; ve2[4 * c + 3] = ec.w * ec.w;
  }

  // ---------------- Sturm bisection: 32 sigma points per half per round ------
  #pragma unroll
  for (int rr = 0; rr < 3; ++rr) {
    float stp = (hi - lo) * (1.0f / 33.0f);
    float sig = fmaf(stp, (float)(j + 1), lo);
    float q = vd[0] - sig;
    int cnt = (q < 0.0f) ? 1 : 0;
    #pragma unroll
    for (int i = 1; i < 32; ++i) {
      float qs = (fabsf(q) < 1e-12f) ? ((q < 0.0f) ? -1e-12f : 1e-12f) : q;
      q = (vd[i] - sig) - ve2[i - 1] * rcp_f(qs);
      cnt += (q < 0.0f) ? 1 : 0;
    }
    unsigned long long m64 = __ballot(cnt >= 1);
    unsigned hm = (unsigned)(m64 >> (half * 32));   // this half's 32 bits
    int b = (hm == 0u) ? 32 : (__ffs(hm) - 1);
    float nlo = fmaf(stp, (float)b, lo);
    float nhi = (b == 32) ? hi : fmaf(stp, (float)(b + 1), lo);
    lo = nlo; hi = nhi;
  }

  if (j == 0) out[mol] = 0.5f * (lo + hi);
}

extern "C" void kernel_launch(void* const* d_in, const int* in_sizes, int n_in,
                              void* d_out, int out_size, void* d_ws, size_t ws_size,
                              hipStream_t stream) {
  const float* A = (const float*)d_in[0];
  float* out = (float*)d_out;
  int n_atoms = in_sizes[1];          // 262144
  int M = n_atoms / 32;               // 8192 molecules
  int blocks = (M + 7) / 8;           // 8 molecules per 256-thread block (2/wave)
  hipLaunchKernelGGL(Correlation_85134841741354_kernel,
                     dim3(blocks), dim3(256), 0, stream, A, out, M);
}

// Round 5
// 264.975 us; speedup vs baseline: 1.7181x; 1.1759x over previous
//
#include <hip/hip_runtime.h>
#include <hip/hip_bf16.h>

#define DEVINL __device__ __forceinline__

DEVINL float rcp_f(float x) { return __builtin_amdgcn_rcpf(x); }

// compiler-level memory barrier: forces LDS stores to be emitted and kills
// stale-value forwarding across it (R4-proven). No instruction generated;
// within-wave DS ordering is guaranteed by hardware.
#define LDS_FENCE() __asm__ volatile("" ::: "memory")

// DPP cross-lane move within rows of 16 lanes (VALU pipe, no DS latency).
template<int CTRL>
DEVINL float dpp_mov(float x) {
  return __int_as_float(__builtin_amdgcn_update_dpp(
      0, __float_as_int(x), CTRL, 0xF, 0xF, true));
}
// Bit-exact xor-butterfly sum/min/max over a 16-lane group:
// xor1 = quad_perm[1,0,3,2]=0xB1, xor2 = quad_perm[2,3,0,1]=0x4E,
// xor4-equiv = row_half_mirror (0x141), xor8-equiv = row_mirror (0x140)
// (mirror levels are exact because values are group-uniform at that level).
DEVINL float group_sum(float x) {
  x += dpp_mov<0xB1>(x);
  x += dpp_mov<0x4E>(x);
  x += dpp_mov<0x141>(x);
  x += dpp_mov<0x140>(x);
  return x;
}
DEVINL float group_min(float x) {
  x = fminf(x, dpp_mov<0xB1>(x));
  x = fminf(x, dpp_mov<0x4E>(x));
  x = fminf(x, dpp_mov<0x141>(x));
  x = fminf(x, dpp_mov<0x140>(x));
  return x;
}
DEVINL float group_max(float x) {
  x = fmaxf(x, dpp_mov<0xB1>(x));
  x = fmaxf(x, dpp_mov<0x4E>(x));
  x = fmaxf(x, dpp_mov<0x141>(x));
  x = fmaxf(x, dpp_mov<0x140>(x));
  return x;
}

// One Householder step at compile-time pivot K. 16 lanes per molecule; lane
// l of a group owns rows l (r0) and l+16 (r1) of its molecule's 32x32 Gram
// matrix. v/w broadcast via per-group LDS staging + float4 chunk reads.
template<int K>
DEVINL void house_step(float (&r0)[32], float (&r1)[32], int l, int lane,
                       float* vbuf, float* wbuf, float* dbuf, float* ebuf) {
  constexpr int C0 = (K + 1) / 4;             // first float4 chunk touching v

  float xm0, xm1;
  if constexpr (K < 15) xm0 = (l > K) ? r0[K] : 0.0f;  // row l active iff l>K
  else                  xm0 = 0.0f;                    // rows 0..15 all frozen
  if constexpr (K < 16) xm1 = r1[K];                   // rows 16..31 all active
  else                  xm1 = (l > K - 16) ? r1[K] : 0.0f;

  float nn = group_sum(xm0 * xm0 + xm1 * xm1);         // ||x||^2, uniform
  float xsrc = (K + 1 < 16) ? xm0 : xm1;               // compile-time select
  float x0 = __shfl(xsrc, (lane & 48) + ((K + 1) & 15), 64);
  float alpha = -copysignf(sqrtf(nn), x0);             // new subdiagonal e_K
  float denom = nn - alpha * x0;                       // >= 0
  float beta = (denom > 1e-20f) ? rcp_f(denom) : 0.0f; // 2 / v'v

  float v0, v1;
  if constexpr (K + 1 < 16) {
    v0 = xm0 - ((l == K + 1) ? alpha : 0.0f);          // pivot row in r0
    v1 = xm1;
  } else {
    v0 = 0.0f;
    v1 = xm1 - ((l == K + 1 - 16) ? alpha : 0.0f);     // pivot row in r1
  }
  vbuf[l] = v0; vbuf[l + 16] = v1;
  LDS_FENCE();

  float4 vc[8];
  #pragma unroll
  for (int c = C0; c < 8; ++c) vc[c] = *(const float4*)(vbuf + 4 * c);

  float p0 = 0.0f;
  if constexpr (K < 15) {                              // r0 rows still live
    float a0 = 0.0f, a1 = 0.0f;
    #pragma unroll
    for (int c = C0; c < 8; ++c) {
      a0 = fmaf(r0[4 * c + 0], vc[c].x, a0); a1 = fmaf(r0[4 * c + 1], vc[c].y, a1);
      a0 = fmaf(r0[4 * c + 2], vc[c].z, a0); a1 = fmaf(r0[4 * c + 3], vc[c].w, a1);
    }
    p0 = a0 + a1;
  }
  float b0 = 0.0f, b1 = 0.0f;
  #pragma unroll
  for (int c = C0; c < 8; ++c) {
    b0 = fmaf(r1[4 * c + 0], vc[c].x, b0); b1 = fmaf(r1[4 * c + 1], vc[c].y, b1);
    b0 = fmaf(r1[4 * c + 2], vc[c].z, b0); b1 = fmaf(r1[4 * c + 3], vc[c].w, b1);
  }
  float p1 = b0 + b1;

  float pb0 = beta * p0, pb1 = beta * p1;
  float g = group_sum(pb0 * v0 + pb1 * v1);            // v' (beta C v)
  float c2 = 0.5f * beta * g;
  float w0 = fmaf(-c2, v0, pb0);
  float w1 = fmaf(-c2, v1, pb1);
  float w0a, w1a;                                      // freeze finished rows
  if constexpr (K < 15) w0a = (l > K) ? w0 : 0.0f; else w0a = 0.0f;
  if constexpr (K < 16) w1a = w1; else w1a = (l > K - 16) ? w1 : 0.0f;
  wbuf[l] = w0a; wbuf[l + 16] = w1a;
  LDS_FENCE();

  #pragma unroll
  for (int c = C0; c < 8; ++c) {
    float4 wc = *(const float4*)(wbuf + 4 * c);
    if constexpr (K < 15) {
      r0[4 * c + 0] -= v0 * wc.x + w0a * vc[c].x;
      r0[4 * c + 1] -= v0 * wc.y + w0a * vc[c].y;
      r0[4 * c + 2] -= v0 * wc.z + w0a * vc[c].z;
      r0[4 * c + 3] -= v0 * wc.w + w0a * vc[c].w;
    }
    r1[4 * c + 0] -= v1 * wc.x + w1a * vc[c].x;
    r1[4 * c + 1] -= v1 * wc.y + w1a * vc[c].y;
    r1[4 * c + 2] -= v1 * wc.z + w1a * vc[c].z;
    r1[4 * c + 3] -= v1 * wc.w + w1a * vc[c].w;
  }

  if constexpr (K < 16) {
    if (l == K) { dbuf[K] = r0[K]; ebuf[K] = alpha; }
  } else {
    if (l == K - 16) { dbuf[K] = r1[K]; ebuf[K] = alpha; }
  }
}

template<int K>
DEVINL void house_all(float (&r0)[32], float (&r1)[32], int l, int lane,
                      float* vbuf, float* wbuf, float* dbuf, float* ebuf) {
  house_step<K>(r0, r1, l, lane, vbuf, wbuf, dbuf, ebuf);
  if constexpr (K < 30) house_all<K + 1>(r0, r1, l, lane, vbuf, wbuf, dbuf, ebuf);
}

__global__ __launch_bounds__(256) void Correlation_85134841741354_kernel(
    const float* __restrict__ A, float* __restrict__ out, int M) {
  const int lane = threadIdx.x & 63;
  const int wave = threadIdx.x >> 6;
  const int l    = lane & 15;            // lane within its 16-lane group
  const int grp  = lane >> 4;            // group (molecule) within the wave
  const int mol  = blockIdx.x * 16 + wave * 4 + grp;
  if (mol >= M) return;                  // M % 16 == 0: wave-uniform

  // per-group scratch; 36-float rows keep float4 alignment
  __shared__ float ldsv[16][36], ldsw[16][36], ldsd[16][36], ldse[16][36];
  const int slot = wave * 4 + grp;
  float* vbuf = ldsv[slot];
  float* wbuf = ldsw[slot];
  float* dbuf = ldsd[slot];
  float* ebuf = ldse[slot];

  const float* Am   = A + (size_t)mol * (32 * 128);
  const float* own0 = Am + l * 128;          // row l
  const float* own1 = own0 + 16 * 128;       // row l+16

  // ---------------- Gram: rX[m] = sum_f A[row][f] * A[m][f] ------------------
  float r0[32], r1[32];
  #pragma unroll
  for (int m = 0; m < 32; ++m) { r0[m] = 0.0f; r1[m] = 0.0f; }

  #pragma unroll 1
  for (int fb = 0; fb < 8; ++fb) {           // 16 features per block
    float4 o0 = *(const float4*)(own0 + fb * 16 + 0);
    float4 o1 = *(const float4*)(own0 + fb * 16 + 4);
    float4 o2 = *(const float4*)(own0 + fb * 16 + 8);
    float4 o3 = *(const float4*)(own0 + fb * 16 + 12);
    float4 q0 = *(const float4*)(own1 + fb * 16 + 0);
    float4 q1 = *(const float4*)(own1 + fb * 16 + 4);
    float4 q2 = *(const float4*)(own1 + fb * 16 + 8);
    float4 q3 = *(const float4*)(own1 + fb * 16 + 12);
    #pragma unroll
    for (int m = 0; m < 32; ++m) {
      const float* bm = Am + m * 128 + fb * 16;   // uniform within group
      float4 c0 = *(const float4*)(bm + 0);
      float4 c1 = *(const float4*)(bm + 4);
      float4 c2 = *(const float4*)(bm + 8);
      float4 c3 = *(const float4*)(bm + 12);
      float s = r0[m];
      s = fmaf(o0.x, c0.x, s); s = fmaf(o0.y, c0.y, s);
      s = fmaf(o0.z, c0.z, s); s = fmaf(o0.w, c0.w, s);
      s = fmaf(o1.x, c1.x, s); s = fmaf(o1.y, c1.y, s);
      s = fmaf(o1.z, c1.z, s); s = fmaf(o1.w, c1.w, s);
      s = fmaf(o2.x, c2.x, s); s = fmaf(o2.y, c2.y, s);
      s = fmaf(o2.z, c2.z, s); s = fmaf(o2.w, c2.w, s);
      s = fmaf(o3.x, c3.x, s); s = fmaf(o3.y, c3.y, s);
      s = fmaf(o3.z, c3.z, s); s = fmaf(o3.w, c3.w, s);
      r0[m] = s;
      float t = r1[m];
      t = fmaf(q0.x, c0.x, t); t = fmaf(q0.y, c0.y, t);
      t = fmaf(q0.z, c0.z, t); t = fmaf(q0.w, c0.w, t);
      t = fmaf(q1.x, c1.x, t); t = fmaf(q1.y, c1.y, t);
      t = fmaf(q1.z, c1.z, t); t = fmaf(q1.w, c1.w, t);
      t = fmaf(q2.x, c2.x, t); t = fmaf(q2.y, c2.y, t);
      t = fmaf(q2.z, c2.z, t); t = fmaf(q2.w, c2.w, t);
      t = fmaf(q3.x, c3.x, t); t = fmaf(q3.y, c3.y, t);
      t = fmaf(q3.z, c3.z, t); t = fmaf(q3.w, c3.w, t);
      r1[m] = t;
    }
  }

  // ---------------- Householder tridiagonalization ---------------------------
  house_all<0>(r0, r1, l, lane, vbuf, wbuf, dbuf, ebuf);
  if (l == 15) { dbuf[31] = r1[31]; ebuf[31] = 0.0f; }
  LDS_FENCE();

  // ---------------- Gershgorin bracket ---------------------------------------
  float d0 = dbuf[l], d1 = dbuf[l + 16];
  float eh0 = ebuf[l];
  float el0 = (l > 0) ? ebuf[l - 1] : 0.0f;
  float eh1 = ebuf[l + 16];                  // ebuf[31] = 0
  float el1 = ebuf[l + 15];                  // l=0 -> ebuf[15] (edge 15-16)
  float rad0 = fabsf(eh0) + fabsf(el0);
  float rad1 = fabsf(eh1) + fabsf(el1);
  float glo = group_min(fminf(d0 - rad0, d1 - rad1));
  float ghi = group_max(fmaxf(d0 + rad0, d1 + rad1));
  float lo = fmaxf(glo - 1e-3f, 0.0f);       // C = A A' is PSD
  float hi = ghi + 1e-3f;

  // tridiagonal into registers (uniform per group)
  float vd[32], ve2[32];
  #pragma unroll
  for (int c = 0; c < 8; ++c) {
    float4 dc = *(const float4*)(dbuf + 4 * c);
    float4 ec = *(const float4*)(ebuf + 4 * c);
    vd[4 * c + 0] = dc.x; vd[4 * c + 1] = dc.y;
    vd[4 * c + 2] = dc.z; vd[4 * c + 3] = dc.w;
    ve2[4 * c + 0] = ec.x * ec.x; ve2[4 * c + 1] = ec.y * ec.y;
    ve2[4 * c + 2] = ec.z * ec.z; ve2[4 * c + 3] = ec.w * ec.w;
  }

  // ---------------- Sturm bisection: 16 sigma points / round -----------------
  #pragma unroll
  for (int rr = 0; rr < 3; ++rr) {
    float stp = (hi - lo) * (1.0f / 17.0f);
    float sig = fmaf(stp, (float)(l + 1), lo);
    float q = vd[0] - sig;
    int cnt = (q < 0.0f) ? 1 : 0;
    #pragma unroll
    for (int i = 1; i < 32; ++i) {
      float qs = (fabsf(q) < 1e-12f) ? ((q < 0.0f) ? -1e-12f : 1e-12f) : q;
      q = (vd[i] - sig) - ve2[i - 1] * rcp_f(qs);
      cnt += (q < 0.0f) ? 1 : 0;
    }
    unsigned long long m64 = __ballot(cnt >= 1);
    unsigned hm = (unsigned)((m64 >> (grp * 16)) & 0xFFFFu);
    int b = (hm == 0u) ? 16 : (__ffs(hm) - 1);
    float nhi = (b == 16) ? hi : fmaf(stp, (float)(b + 1), lo);
    lo = fmaf(stp, (float)b, lo);
    hi = nhi;
  }

  if (l == 0) out[mol] = 0.5f * (lo + hi);
}

extern "C" void kernel_launch(void* const* d_in, const int* in_sizes, int n_in,
                              void* d_out, int out_size, void* d_ws, size_t ws_size,
                              hipStream_t stream) {
  const float* A = (const float*)d_in[0];
  float* out = (float*)d_out;
  int n_atoms = in_sizes[1];          // 262144
  int M = n_atoms / 32;               // 8192 molecules
  int blocks = (M + 15) / 16;         // 16 molecules per 256-thread block
  hipLaunchKernelGGL(Correlation_85134841741354_kernel,
                     dim3(blocks), dim3(256), 0, stream, A, out, M);
}

// Round 6
// 213.169 us; speedup vs baseline: 2.1356x; 1.2430x over previous
//
#include <hip/hip_runtime.h>
#include <hip/hip_bf16.h>

#define DEVINL __device__ __forceinline__

typedef __attribute__((ext_vector_type(8))) short short8;   // 8 bf16 (4 VGPRs)
typedef __attribute__((ext_vector_type(4))) float f32x4;    // MFMA acc

DEVINL float rcp_f(float x) { return __builtin_amdgcn_rcpf(x); }

// compiler-level memory barrier: forces LDS stores to be emitted and kills
// stale-value forwarding (R4-proven). No instruction generated; within-wave
// DS ordering is guaranteed by hardware (DS pipe is in-order per wave).
#define LDS_FENCE() __asm__ volatile("" ::: "memory")

// DPP cross-lane moves within 16-lane rows (VALU pipe, no DS latency).
template<int CTRL>
DEVINL float dpp_mov(float x) {
  return __int_as_float(__builtin_amdgcn_update_dpp(
      0, __float_as_int(x), CTRL, 0xF, 0xF, true));
}
// xor-butterfly reduce over a 16-lane group (R5-proven bit-exact).
DEVINL float group_sum(float x) {
  x += dpp_mov<0xB1>(x);   // quad_perm xor1
  x += dpp_mov<0x4E>(x);   // quad_perm xor2
  x += dpp_mov<0x141>(x);  // row_half_mirror
  x += dpp_mov<0x140>(x);  // row_mirror
  return x;
}
DEVINL float group_min(float x) {
  x = fminf(x, dpp_mov<0xB1>(x));
  x = fminf(x, dpp_mov<0x4E>(x));
  x = fminf(x, dpp_mov<0x141>(x));
  x = fminf(x, dpp_mov<0x140>(x));
  return x;
}
DEVINL float group_max(float x) {
  x = fmaxf(x, dpp_mov<0xB1>(x));
  x = fmaxf(x, dpp_mov<0x4E>(x));
  x = fmaxf(x, dpp_mov<0x141>(x));
  x = fmaxf(x, dpp_mov<0x140>(x));
  return x;
}

// fp32 -> bf16 hi (round-half-up) + exact fp32 residual (Sterbenz: f-hi exact)
DEVINL short bf_hi(float f, float& rem) {
  unsigned u = __float_as_uint(f);
  unsigned rh = (u + 0x8000u) >> 16;
  rem = f - __uint_as_float(rh << 16);
  return (short)rh;
}
DEVINL short bf_of(float f) {
  return (short)((__float_as_uint(f) + 0x8000u) >> 16);
}
DEVINL void cvt_hilo(float4 fa, float4 fb, short8& h, short8& lo) {
  float rm;
  h[0] = bf_hi(fa.x, rm); lo[0] = bf_of(rm);
  h[1] = bf_hi(fa.y, rm); lo[1] = bf_of(rm);
  h[2] = bf_hi(fa.z, rm); lo[2] = bf_of(rm);
  h[3] = bf_hi(fa.w, rm); lo[3] = bf_of(rm);
  h[4] = bf_hi(fb.x, rm); lo[4] = bf_of(rm);
  h[5] = bf_hi(fb.y, rm); lo[5] = bf_of(rm);
  h[6] = bf_hi(fb.z, rm); lo[6] = bf_of(rm);
  h[7] = bf_hi(fb.w, rm); lo[7] = bf_of(rm);
}
DEVINL f32x4 mfma_bf16(short8 a, short8 b, f32x4 c) {
  return __builtin_amdgcn_mfma_f32_16x16x32_bf16(a, b, c, 0, 0, 0);
}

// ---------- Householder step at compile-time pivot K ------------------------
// 16 lanes per molecule; lane l owns rows l (r0) and l+16 (r1) of its 32x32
// Gram matrix. v broadcast via LDS; w reconstructed from stored p = C*v
// (w = beta*p - c2*v), saving one LDS roundtrip. Frozen rows' junk p values
// only ever multiply v_m = 0 or pollute never-again-read frozen columns.
template<int K>
DEVINL void house_step(float (&r0)[32], float (&r1)[32], int l, int lane,
                       float* vbuf, float* pbuf, float* dbuf, float* ebuf) {
  constexpr int C0 = (K + 1) / 4;             // first float4 chunk touching v

  float xm0, xm1;
  if constexpr (K < 15) xm0 = (l > K) ? r0[K] : 0.0f;
  else                  xm0 = 0.0f;           // rows 0..15 all frozen
  if constexpr (K < 16) xm1 = r1[K];          // rows 16..31 all active
  else                  xm1 = (l > K - 16) ? r1[K] : 0.0f;

  float xsrc = (K + 1 < 16) ? xm0 : xm1;      // compile-time select
  float x0 = __shfl(xsrc, (lane & 48) + ((K + 1) & 15), 64);  // DS, overlaps DPP
  float nn = group_sum(xm0 * xm0 + xm1 * xm1);
  float alpha = -copysignf(sqrtf(nn), x0);    // new subdiagonal e_K
  float denom = nn - alpha * x0;              // >= 0
  float beta = (denom > 1e-20f) ? rcp_f(denom) : 0.0f;  // 2 / v'v

  float v0, v1;
  if constexpr (K + 1 < 16) {
    v0 = xm0 - ((l == K + 1) ? alpha : 0.0f);
    v1 = xm1;
  } else {
    v0 = 0.0f;
    v1 = xm1 - ((l == K + 1 - 16) ? alpha : 0.0f);
  }
  vbuf[l] = v0; vbuf[l + 16] = v1;
  LDS_FENCE();

  float4 vc[8];
  #pragma unroll
  for (int c = C0; c < 8; ++c) vc[c] = *(const float4*)(vbuf + 4 * c);

  float p0 = 0.0f;
  if constexpr (K < 15) {
    float a0 = 0.0f, a1 = 0.0f;
    #pragma unroll
    for (int c = C0; c < 8; ++c) {
      a0 = fmaf(r0[4 * c + 0], vc[c].x, a0); a1 = fmaf(r0[4 * c + 1], vc[c].y, a1);
      a0 = fmaf(r0[4 * c + 2], vc[c].z, a0); a1 = fmaf(r0[4 * c + 3], vc[c].w, a1);
    }
    p0 = a0 + a1;
  }
  float b0 = 0.0f, b1 = 0.0f;
  #pragma unroll
  for (int c = C0; c < 8; ++c) {
    b0 = fmaf(r1[4 * c + 0], vc[c].x, b0); b1 = fmaf(r1[4 * c + 1], vc[c].y, b1);
    b0 = fmaf(r1[4 * c + 2], vc[c].z, b0); b1 = fmaf(r1[4 * c + 3], vc[c].w, b1);
  }
  float p1 = b0 + b1;

  pbuf[l] = p0; pbuf[l + 16] = p1;            // store raw p = C*v
  LDS_FENCE();
  float G = group_sum(v0 * p0 + v1 * p1);     // overlaps p readback
  float c2 = 0.5f * beta * beta * G;

  float w0 = fmaf(-c2, v0, beta * p0);        // this lane's row weights
  float w1 = fmaf(-c2, v1, beta * p1);

  #pragma unroll
  for (int c = C0; c < 8; ++c) {
    float4 pc = *(const float4*)(pbuf + 4 * c);
    float wx = fmaf(-c2, vc[c].x, beta * pc.x);
    float wy = fmaf(-c2, vc[c].y, beta * pc.y);
    float wz = fmaf(-c2, vc[c].z, beta * pc.z);
    float ww = fmaf(-c2, vc[c].w, beta * pc.w);
    if constexpr (K < 15) {
      r0[4 * c + 0] -= v0 * wx + w0 * vc[c].x;
      r0[4 * c + 1] -= v0 * wy + w0 * vc[c].y;
      r0[4 * c + 2] -= v0 * wz + w0 * vc[c].z;
      r0[4 * c + 3] -= v0 * ww + w0 * vc[c].w;
    }
    r1[4 * c + 0] -= v1 * wx + w1 * vc[c].x;
    r1[4 * c + 1] -= v1 * wy + w1 * vc[c].y;
    r1[4 * c + 2] -= v1 * wz + w1 * vc[c].z;
    r1[4 * c + 3] -= v1 * ww + w1 * vc[c].w;
  }

  // record d_K/e_K (diagonal untouched by this step's update: v_K = 0)
  if constexpr (K < 16) {
    if (l == K) { dbuf[K] = r0[K]; ebuf[K] = alpha; }
  } else {
    if (l == K - 16) { dbuf[K] = r1[K]; ebuf[K] = alpha; }
  }
}

template<int K>
DEVINL void house_all(float (&r0)[32], float (&r1)[32], int l, int lane,
                      float* vbuf, float* pbuf, float* dbuf, float* ebuf) {
  house_step<K>(r0, r1, l, lane, vbuf, pbuf, dbuf, ebuf);
  if constexpr (K < 30) house_all<K + 1>(r0, r1, l, lane, vbuf, pbuf, dbuf, ebuf);
}

__global__ __launch_bounds__(256) void Correlation_85134841741354_kernel(
    const float* __restrict__ A, float* __restrict__ out, int M) {
  const int lane = threadIdx.x & 63;
  const int wave = threadIdx.x >> 6;
  const int q    = lane >> 4;            // quad == eigensolve group
  const int t    = lane & 15;            // lane within group / MFMA row index
  const int molbase = blockIdx.x * 16 + wave * 4;
  if (molbase >= M) return;              // M % 16 == 0

  // per-wave C tile (stride 36: MFMA writes land 2-way only -> free)
  __shared__ float lds_C[4][32 * 36 + 8];
  // per-group scratch, stride 48 (bases alternate 0/16 banks -> 2-way, free)
  __shared__ float ldsv[16][48], ldsp[16][48], ldsd[16][48], ldse[16][48];
  float* Ct   = lds_C[wave];
  const int slot = wave * 4 + q;
  float* vbuf = ldsv[slot];
  float* pbuf = ldsp[slot];
  float* dbuf = ldsd[slot];
  float* ebuf = ldse[slot];

  // ---------------- Gram via MFMA (hi/lo bf16 split), 1 molecule at a time ---
  float r0[32], r1[32];
  #pragma unroll
  for (int m = 0; m < 32; ++m) { r0[m] = 0.0f; r1[m] = 0.0f; }

  #pragma unroll 1
  for (int g = 0; g < 4; ++g) {
    const float* Am = A + (size_t)(molbase + g) * (32 * 128);
    f32x4 acc00 = {0.f, 0.f, 0.f, 0.f}, acc01 = {0.f, 0.f, 0.f, 0.f};
    f32x4 acc10 = {0.f, 0.f, 0.f, 0.f}, acc11 = {0.f, 0.f, 0.f, 0.f};
    #pragma unroll
    for (int c = 0; c < 4; ++c) {        // K chunks of 32 features
      const float* pr0 = Am + t * 128        + 32 * c + 8 * q;  // A-rows 0..15
      const float* pr1 = Am + (t + 16) * 128 + 32 * c + 8 * q;  // A-rows 16..31
      float4 fa0 = *(const float4*)(pr0);
      float4 fb0 = *(const float4*)(pr0 + 4);
      float4 fa1 = *(const float4*)(pr1);
      float4 fb1 = *(const float4*)(pr1 + 4);
      short8 h0, l0, h1, l1;
      cvt_hilo(fa0, fb0, h0, l0);
      cvt_hilo(fa1, fb1, h1, l1);
      // C = (hi+lo)(hi+lo)^T  ~=  hi hi^T + hi lo^T + lo hi^T  (drop lo lo^T)
      acc00 = mfma_bf16(h0, h0, acc00); acc00 = mfma_bf16(h0, l0, acc00); acc00 = mfma_bf16(l0, h0, acc00);
      acc01 = mfma_bf16(h0, h1, acc01); acc01 = mfma_bf16(h0, l1, acc01); acc01 = mfma_bf16(l0, h1, acc01);
      acc10 = mfma_bf16(h1, h0, acc10); acc10 = mfma_bf16(h1, l0, acc10); acc10 = mfma_bf16(l1, h0, acc10);
      acc11 = mfma_bf16(h1, h1, acc11); acc11 = mfma_bf16(h1, l1, acc11); acc11 = mfma_bf16(l1, h1, acc11);
    }
    // C/D layout: col = lane&15, row = (lane>>4)*4 + reg  [HW-verified]
    #pragma unroll
    for (int reg = 0; reg < 4; ++reg) {
      Ct[(4 * q + reg) * 36 + t]           = acc00[reg];
      Ct[(4 * q + reg) * 36 + 16 + t]      = acc01[reg];
      Ct[(16 + 4 * q + reg) * 36 + t]      = acc10[reg];
      Ct[(16 + 4 * q + reg) * 36 + 16 + t] = acc11[reg];
    }
    LDS_FENCE();
    if (q == g) {                         // this group's molecule: grab rows
      #pragma unroll
      for (int c = 0; c < 8; ++c) {
        float4 a = *(const float4*)(Ct + t * 36 + 4 * c);
        r0[4 * c + 0] = a.x; r0[4 * c + 1] = a.y;
        r0[4 * c + 2] = a.z; r0[4 * c + 3] = a.w;
        float4 b = *(const float4*)(Ct + (t + 16) * 36 + 4 * c);
        r1[4 * c + 0] = b.x; r1[4 * c + 1] = b.y;
        r1[4 * c + 2] = b.z; r1[4 * c + 3] = b.w;
      }
    }
    LDS_FENCE();                          // order reads before next g's writes
  }

  // ---------------- Householder tridiagonalization ---------------------------
  house_all<0>(r0, r1, t, lane, vbuf, pbuf, dbuf, ebuf);
  if (t == 15) { dbuf[31] = r1[31]; ebuf[31] = 0.0f; }
  LDS_FENCE();

  // ---------------- Gershgorin bracket ---------------------------------------
  float d0 = dbuf[t], d1 = dbuf[t + 16];
  float eh0 = ebuf[t];
  float el0 = (t > 0) ? ebuf[t - 1] : 0.0f;
  float eh1 = ebuf[t + 16];                  // ebuf[31] = 0
  float el1 = ebuf[t + 15];                  // t=0 -> edge (15,16)
  float rad0 = fabsf(eh0) + fabsf(el0);
  float rad1 = fabsf(eh1) + fabsf(el1);
  float glo = group_min(fminf(d0 - rad0, d1 - rad1));
  float ghi = group_max(fmaxf(d0 + rad0, d1 + rad1));
  float lo = fmaxf(glo - 1e-3f, 0.0f);       // C = A A' is PSD
  float hi = ghi + 1e-3f;

  // tridiagonal into registers (uniform per group)
  float vd[32], ve2[32];
  #pragma unroll
  for (int c = 0; c < 8; ++c) {
    float4 dc = *(const float4*)(dbuf + 4 * c);
    float4 ec = *(const float4*)(ebuf + 4 * c);
    vd[4 * c + 0] = dc.x; vd[4 * c + 1] = dc.y;
    vd[4 * c + 2] = dc.z; vd[4 * c + 3] = dc.w;
    ve2[4 * c + 0] = ec.x * ec.x; ve2[4 * c + 1] = ec.y * ec.y;
    ve2[4 * c + 2] = ec.z * ec.z; ve2[4 * c + 3] = ec.w * ec.w;
  }

  // ---------------- Sturm bisection: 16 sigma points / round -----------------
  #pragma unroll
  for (int rr = 0; rr < 3; ++rr) {
    float stp = (hi - lo) * (1.0f / 17.0f);
    float sig = fmaf(stp, (float)(t + 1), lo);
    float qq = vd[0] - sig;
    int cnt = (qq < 0.0f) ? 1 : 0;
    #pragma unroll
    for (int i = 1; i < 32; ++i) {
      float qs = (fabsf(qq) < 1e-12f) ? ((qq < 0.0f) ? -1e-12f : 1e-12f) : qq;
      qq = (vd[i] - sig) - ve2[i - 1] * rcp_f(qs);
      cnt += (qq < 0.0f) ? 1 : 0;
    }
    unsigned long long m64 = __ballot(cnt >= 1);
    unsigned hm = (unsigned)((m64 >> (q * 16)) & 0xFFFFu);
    int b = (hm == 0u) ? 16 : (__ffs(hm) - 1);
    float nhi = (b == 16) ? hi : fmaf(stp, (float)(b + 1), lo);
    lo = fmaf(stp, (float)b, lo);
    hi = nhi;
  }

  if (t == 0) out[molbase + q] = 0.5f * (lo + hi);
}

extern "C" void kernel_launch(void* const* d_in, const int* in_sizes, int n_in,
                              void* d_out, int out_size, void* d_ws, size_t ws_size,
                              hipStream_t stream) {
  const float* A = (const float*)d_in[0];
  float* out = (float*)d_out;
  int n_atoms = in_sizes[1];          // 262144
  int M = n_atoms / 32;               // 8192 molecules
  int blocks = (M + 15) / 16;         // 16 molecules per 256-thread block
  hipLaunchKernelGGL(Correlation_85134841741354_kernel,
                     dim3(blocks), dim3(256), 0, stream, A, out, M);
}

// Round 7
// 208.622 us; speedup vs baseline: 2.1822x; 1.0218x over previous
//
#include <hip/hip_runtime.h>
#include <hip/hip_bf16.h>

#define DEVINL __device__ __forceinline__

typedef __attribute__((ext_vector_type(8))) short short8;   // 8 bf16 (4 VGPRs)
typedef __attribute__((ext_vector_type(4))) float f32x4;    // MFMA acc

DEVINL float rcp_f(float x) { return __builtin_amdgcn_rcpf(x); }

// compiler-level memory barrier: forces LDS stores to be emitted and kills
// stale-value forwarding (R4-proven). No instruction generated; within-wave
// DS ordering is guaranteed by hardware (DS pipe is in-order per wave).
#define LDS_FENCE() __asm__ volatile("" ::: "memory")

// DPP cross-lane moves within 16-lane rows (VALU pipe, no DS latency).
template<int CTRL>
DEVINL float dpp_mov(float x) {
  return __int_as_float(__builtin_amdgcn_update_dpp(
      0, __float_as_int(x), CTRL, 0xF, 0xF, true));
}
// xor-butterfly reduce over a 16-lane group (R5/R6-proven bit-exact).
DEVINL float group_sum(float x) {
  x += dpp_mov<0xB1>(x);   // quad_perm xor1
  x += dpp_mov<0x4E>(x);   // quad_perm xor2
  x += dpp_mov<0x141>(x);  // row_half_mirror
  x += dpp_mov<0x140>(x);  // row_mirror
  return x;
}
DEVINL float group_min(float x) {
  x = fminf(x, dpp_mov<0xB1>(x));
  x = fminf(x, dpp_mov<0x4E>(x));
  x = fminf(x, dpp_mov<0x141>(x));
  x = fminf(x, dpp_mov<0x140>(x));
  return x;
}
DEVINL float group_max(float x) {
  x = fmaxf(x, dpp_mov<0xB1>(x));
  x = fmaxf(x, dpp_mov<0x4E>(x));
  x = fmaxf(x, dpp_mov<0x141>(x));
  x = fmaxf(x, dpp_mov<0x140>(x));
  return x;
}

// fp32 -> bf16 hi (round-half-up) + exact fp32 residual
DEVINL short bf_hi(float f, float& rem) {
  unsigned u = __float_as_uint(f);
  unsigned rh = (u + 0x8000u) >> 16;
  rem = f - __uint_as_float(rh << 16);
  return (short)rh;
}
DEVINL short bf_of(float f) {
  return (short)((__float_as_uint(f) + 0x8000u) >> 16);
}
DEVINL void cvt_hilo(float4 fa, float4 fb, short8& h, short8& lo) {
  float rm;
  h[0] = bf_hi(fa.x, rm); lo[0] = bf_of(rm);
  h[1] = bf_hi(fa.y, rm); lo[1] = bf_of(rm);
  h[2] = bf_hi(fa.z, rm); lo[2] = bf_of(rm);
  h[3] = bf_hi(fa.w, rm); lo[3] = bf_of(rm);
  h[4] = bf_hi(fb.x, rm); lo[4] = bf_of(rm);
  h[5] = bf_hi(fb.y, rm); lo[5] = bf_of(rm);
  h[6] = bf_hi(fb.z, rm); lo[6] = bf_of(rm);
  h[7] = bf_hi(fb.w, rm); lo[7] = bf_of(rm);
}
DEVINL f32x4 mfma_bf16(short8 a, short8 b, f32x4 c) {
  return __builtin_amdgcn_mfma_f32_16x16x32_bf16(a, b, c, 0, 0, 0);
}

// ---------- Householder step at compile-time pivot K ------------------------
// 16 lanes per molecule; lane l owns rows l (r0) and l+16 (r1). Raw x staged
// to LDS BEFORE the norm reduction (roundtrip overlaps alpha/beta chain);
// pivot element fixed up in-register at constexpr index. Update uses folded
// scalars s_p, s_v (masked for frozen rows). Junk values only ever reach
// frozen columns of active rows, which are never meaningfully read again.
template<int K>
DEVINL void house_step(float (&r0)[32], float (&r1)[32], int l, int lane,
                       float* vbuf, float* pbuf, float* dbuf, float* ebuf) {
  constexpr int C0 = (K + 1) / 4;             // first float4 chunk touching v
  constexpr int PE = (K + 1) & 3;             // pivot element within chunk C0

  float xm0, xm1;
  if constexpr (K < 15) xm0 = (l > K) ? r0[K] : 0.0f;
  else                  xm0 = 0.0f;           // rows 0..15 all frozen
  if constexpr (K < 16) xm1 = r1[K];          // rows 16..31 all active
  else                  xm1 = (l > K - 16) ? r1[K] : 0.0f;

  vbuf[l] = xm0; vbuf[l + 16] = xm1;          // stage RAW x immediately
  LDS_FENCE();

  float xsrc = (K + 1 < 16) ? xm0 : xm1;      // compile-time select
  float x0 = __shfl(xsrc, (lane & 48) + ((K + 1) & 15), 64);
  float nn = group_sum(xm0 * xm0 + xm1 * xm1);

  float4 vc[8];                               // x chunks (read overlaps chain)
  #pragma unroll
  for (int c = C0; c < 8; ++c) vc[c] = *(const float4*)(vbuf + 4 * c);

  float alpha = -copysignf(sqrtf(nn), x0);    // new subdiagonal e_K
  float denom = nn - alpha * x0;              // >= 0
  float beta = (denom > 1e-20f) ? rcp_f(denom) : 0.0f;  // 2 / v'v

  float v0, v1;
  if constexpr (K + 1 < 16) {
    v0 = xm0 - ((l == K + 1) ? alpha : 0.0f);
    v1 = xm1;
  } else {
    v0 = 0.0f;
    v1 = xm1 - ((l == K + 1 - 16) ? alpha : 0.0f);
  }
  // fix the pivot element of the broadcast copy: v = x - alpha*e_{K+1}
  if constexpr (PE == 0)      vc[C0].x -= alpha;
  else if constexpr (PE == 1) vc[C0].y -= alpha;
  else if constexpr (PE == 2) vc[C0].z -= alpha;
  else                        vc[C0].w -= alpha;

  float p0 = 0.0f;
  if constexpr (K < 15) {
    float a0 = 0.0f, a1 = 0.0f;
    #pragma unroll
    for (int c = C0; c < 8; ++c) {
      a0 = fmaf(r0[4 * c + 0], vc[c].x, a0); a1 = fmaf(r0[4 * c + 1], vc[c].y, a1);
      a0 = fmaf(r0[4 * c + 2], vc[c].z, a0); a1 = fmaf(r0[4 * c + 3], vc[c].w, a1);
    }
    p0 = a0 + a1;
  }
  float b0 = 0.0f, b1 = 0.0f;
  #pragma unroll
  for (int c = C0; c < 8; ++c) {
    b0 = fmaf(r1[4 * c + 0], vc[c].x, b0); b1 = fmaf(r1[4 * c + 1], vc[c].y, b1);
    b0 = fmaf(r1[4 * c + 2], vc[c].z, b0); b1 = fmaf(r1[4 * c + 3], vc[c].w, b1);
  }
  float p1 = b0 + b1;

  pbuf[l] = p0; pbuf[l + 16] = p1;            // store raw p = C*v
  LDS_FENCE();
  float G = group_sum(v0 * p0 + v1 * p1);     // overlaps p readback
  float c2 = 0.5f * beta * beta * G;

  // folded update scalars: r -= s_p*p[m] + s_v*v[m]   (== v*w[m] + w*v[m])
  float s_p0 = 0.0f, s_v0 = 0.0f;
  if constexpr (K < 15) {
    bool act0 = (l > K);
    s_p0 = beta * v0;                                       // 0 if frozen
    s_v0 = act0 ? fmaf(-2.0f * c2, v0, beta * p0) : 0.0f;
  }
  float s_p1 = beta * v1;                                   // v1 masked already
  float s_v1;
  if constexpr (K < 16) s_v1 = fmaf(-2.0f * c2, v1, beta * p1);
  else                  s_v1 = (l > K - 16) ? fmaf(-2.0f * c2, v1, beta * p1) : 0.0f;

  #pragma unroll
  for (int c = C0; c < 8; ++c) {
    float4 pc = *(const float4*)(pbuf + 4 * c);
    if constexpr (K < 15) {
      r0[4 * c + 0] -= s_p0 * pc.x + s_v0 * vc[c].x;
      r0[4 * c + 1] -= s_p0 * pc.y + s_v0 * vc[c].y;
      r0[4 * c + 2] -= s_p0 * pc.z + s_v0 * vc[c].z;
      r0[4 * c + 3] -= s_p0 * pc.w + s_v0 * vc[c].w;
    }
    r1[4 * c + 0] -= s_p1 * pc.x + s_v1 * vc[c].x;
    r1[4 * c + 1] -= s_p1 * pc.y + s_v1 * vc[c].y;
    r1[4 * c + 2] -= s_p1 * pc.z + s_v1 * vc[c].z;
    r1[4 * c + 3] -= s_p1 * pc.w + s_v1 * vc[c].w;
  }

  if constexpr (K < 16) {
    if (l == K) { dbuf[K] = r0[K]; ebuf[K] = alpha; }
  } else {
    if (l == K - 16) { dbuf[K] = r1[K]; ebuf[K] = alpha; }
  }
}

template<int K>
DEVINL void house_all(float (&r0)[32], float (&r1)[32], int l, int lane,
                      float* vbuf, float* pbuf, float* dbuf, float* ebuf) {
  house_step<K>(r0, r1, l, lane, vbuf, pbuf, dbuf, ebuf);
  if constexpr (K < 30) house_all<K + 1>(r0, r1, l, lane, vbuf, pbuf, dbuf, ebuf);
}

__global__ __launch_bounds__(256) void Correlation_85134841741354_kernel(
    const float* __restrict__ A, float* __restrict__ out, int M) {
  const int lane = threadIdx.x & 63;
  const int wave = threadIdx.x >> 6;
  const int q    = lane >> 4;            // quad == eigensolve group
  const int t    = lane & 15;            // lane within group / MFMA row index
  const int molbase = blockIdx.x * 16 + wave * 4;
  if (molbase >= M) return;              // M % 16 == 0

  // 4 C-tiles per wave (one per molecule), stride 36 (float4-aligned).
  // 4*4*1160*4B = 72.5 KB/block -> 2 blocks/CU. Tile q's memory is reused as
  // group q's Householder scratch after readback.
  __shared__ float ldsT[4][4][32 * 36 + 8];

  // ---------------- Gram via MFMA (hi/lo bf16 split); NO readback in loop ----
  // Keeps r0/r1 dead during the high-pressure Gram phase (de-spill).
  #pragma unroll 1
  for (int g = 0; g < 4; ++g) {
    const float* Am = A + (size_t)(molbase + g) * (32 * 128);
    f32x4 acc00 = {0.f, 0.f, 0.f, 0.f}, acc01 = {0.f, 0.f, 0.f, 0.f};
    f32x4 acc10 = {0.f, 0.f, 0.f, 0.f}, acc11 = {0.f, 0.f, 0.f, 0.f};
    #pragma unroll
    for (int c = 0; c < 4; ++c) {        // K chunks of 32 features
      const float* pr0 = Am + t * 128        + 32 * c + 8 * q;  // rows 0..15
      const float* pr1 = Am + (t + 16) * 128 + 32 * c + 8 * q;  // rows 16..31
      float4 fa0 = *(const float4*)(pr0);
      float4 fb0 = *(const float4*)(pr0 + 4);
      float4 fa1 = *(const float4*)(pr1);
      float4 fb1 = *(const float4*)(pr1 + 4);
      short8 h0, l0, h1, l1;
      cvt_hilo(fa0, fb0, h0, l0);
      cvt_hilo(fa1, fb1, h1, l1);
      // C = (hi+lo)(hi+lo)^T ~= hi hi^T + hi lo^T + lo hi^T  (drop lo lo^T)
      acc00 = mfma_bf16(h0, h0, acc00); acc00 = mfma_bf16(h0, l0, acc00); acc00 = mfma_bf16(l0, h0, acc00);
      acc01 = mfma_bf16(h0, h1, acc01); acc01 = mfma_bf16(h0, l1, acc01); acc01 = mfma_bf16(l0, h1, acc01);
      acc10 = mfma_bf16(h1, h0, acc10); acc10 = mfma_bf16(h1, l0, acc10); acc10 = mfma_bf16(l1, h0, acc10);
      acc11 = mfma_bf16(h1, h1, acc11); acc11 = mfma_bf16(h1, l1, acc11); acc11 = mfma_bf16(l1, h1, acc11);
    }
    // C/D layout: col = lane&15, row = (lane>>4)*4 + reg  [HW-verified]
    float* tg = &ldsT[wave][g][0];
    #pragma unroll
    for (int reg = 0; reg < 4; ++reg) {
      tg[(4 * q + reg) * 36 + t]           = acc00[reg];
      tg[(4 * q + reg) * 36 + 16 + t]      = acc01[reg];
      tg[(16 + 4 * q + reg) * 36 + t]      = acc10[reg];
      tg[(16 + 4 * q + reg) * 36 + 16 + t] = acc11[reg];
    }
  }
  LDS_FENCE();

  // readback: every group reads its own molecule's rows (one-time)
  float* tq = &ldsT[wave][q][0];
  float r0[32], r1[32];
  #pragma unroll
  for (int c = 0; c < 8; ++c) {
    float4 a = *(const float4*)(tq + t * 36 + 4 * c);
    r0[4 * c + 0] = a.x; r0[4 * c + 1] = a.y;
    r0[4 * c + 2] = a.z; r0[4 * c + 3] = a.w;
    float4 b = *(const float4*)(tq + (t + 16) * 36 + 4 * c);
    r1[4 * c + 0] = b.x; r1[4 * c + 1] = b.y;
    r1[4 * c + 2] = b.z; r1[4 * c + 3] = b.w;
  }
  LDS_FENCE();   // order readback reads before scratch writes (aliased memory)

  // Householder scratch carved from the (now dead) tile q; bases staggered
  // by 8 banks across groups -> worst 2-way (free).
  float* vbuf = tq;
  float* pbuf = tq + 40;
  float* dbuf = tq + 80;
  float* ebuf = tq + 120;

  // ---------------- Householder tridiagonalization ---------------------------
  house_all<0>(r0, r1, t, lane, vbuf, pbuf, dbuf, ebuf);
  if (t == 15) { dbuf[31] = r1[31]; ebuf[31] = 0.0f; }
  LDS_FENCE();

  // ---------------- Gershgorin bracket ---------------------------------------
  float d0 = dbuf[t], d1 = dbuf[t + 16];
  float eh0 = ebuf[t];
  float el0 = (t > 0) ? ebuf[t - 1] : 0.0f;
  float eh1 = ebuf[t + 16];                  // ebuf[31] = 0
  float el1 = ebuf[t + 15];                  // t=0 -> edge (15,16)
  float rad0 = fabsf(eh0) + fabsf(el0);
  float rad1 = fabsf(eh1) + fabsf(el1);
  float glo = group_min(fminf(d0 - rad0, d1 - rad1));
  float ghi = group_max(fmaxf(d0 + rad0, d1 + rad1));
  float lo = fmaxf(glo - 1e-3f, 0.0f);       // C = A A' is PSD
  float hi = ghi + 1e-3f;

  // tridiagonal into registers (uniform per group)
  float vd[32], ve2[32];
  #pragma unroll
  for (int c = 0; c < 8; ++c) {
    float4 dc = *(const float4*)(dbuf + 4 * c);
    float4 ec = *(const float4*)(ebuf + 4 * c);
    vd[4 * c + 0] = dc.x; vd[4 * c + 1] = dc.y;
    vd[4 * c + 2] = dc.z; vd[4 * c + 3] = dc.w;
    ve2[4 * c + 0] = ec.x * ec.x; ve2[4 * c + 1] = ec.y * ec.y;
    ve2[4 * c + 2] = ec.z * ec.z; ve2[4 * c + 3] = ec.w * ec.w;
  }

  // ---------------- Sturm bisection: 16 sigma points / round -----------------
  #pragma unroll
  for (int rr = 0; rr < 3; ++rr) {
    float stp = (hi - lo) * (1.0f / 17.0f);
    float sig = fmaf(stp, (float)(t + 1), lo);
    float qq = vd[0] - sig;
    int cnt = (qq < 0.0f) ? 1 : 0;
    #pragma unroll
    for (int i = 1; i < 32; ++i) {
      float qs = (fabsf(qq) < 1e-12f) ? ((qq < 0.0f) ? -1e-12f : 1e-12f) : qq;
      qq = (vd[i] - sig) - ve2[i - 1] * rcp_f(qs);
      cnt += (qq < 0.0f) ? 1 : 0;
    }
    unsigned long long m64 = __ballot(cnt >= 1);
    unsigned hm = (unsigned)((m64 >> (q * 16)) & 0xFFFFu);
    int b = (hm == 0u) ? 16 : (__ffs(hm) - 1);
    float nhi = (b == 16) ? hi : fmaf(stp, (float)(b + 1), lo);
    lo = fmaf(stp, (float)b, lo);
    hi = nhi;
  }

  if (t == 0) out[molbase + q] = 0.5f * (lo + hi);
}

extern "C" void kernel_launch(void* const* d_in, const int* in_sizes, int n_in,
                              void* d_out, int out_size, void* d_ws, size_t ws_size,
                              hipStream_t stream) {
  const float* A = (const float*)d_in[0];
  float* out = (float*)d_out;
  int n_atoms = in_sizes[1];          // 262144
  int M = n_atoms / 32;               // 8192 molecules
  int blocks = (M + 15) / 16;         // 16 molecules per 256-thread block
  hipLaunchKernelGGL(Correlation_85134841741354_kernel,
                     dim3(blocks), dim3(256), 0, stream, A, out, M);
}